// Round 1
// baseline (888.271 us; speedup 1.0000x reference)
//
#include <hip/hip_runtime.h>
#include <hip/hip_bf16.h>

// 2-layer LSTM, B=512 T=128 D=1024 H=128, fp32 in/out.
// Phase A (k_prep + k_gemm1): G1[b,t,4H] = feats @ Wih1^T via split-bf16
//   (hi/lo, 3 MFMA terms -> ~fp32 exact). Biases NOT folded (added in phase B).
// Phase B (k_lstm): 32 blocks x 16 batch rows, 8 waves. Whh1 in LDS
//   (fragment-ordered bf16), [Wih2;Whh2] in per-wave register fragments,
//   h1/h2 as fragment-ordered bf16 LDS, c1/c2 in registers. 4 barriers/step,
//   no inter-block communication (batch-parallel recurrence).

using f32x4 = __attribute__((ext_vector_type(4))) float;
using s16x8 = __attribute__((ext_vector_type(8))) short;

#define T_SEQ 128
#define D_IN  1024
#define H_HID 128

__device__ __forceinline__ unsigned short bf16rne(float x) {
  unsigned int b = __builtin_bit_cast(unsigned int, x);
  b = (b + 0x7FFFu + ((b >> 16) & 1u)) >> 16;   // round-to-nearest-even
  return (unsigned short)b;
}
__device__ __forceinline__ float bf16f(unsigned short h) {
  unsigned int b = ((unsigned int)h) << 16;
  return __builtin_bit_cast(float, b);
}
__device__ __forceinline__ float sigf(float x) {
  return __builtin_amdgcn_rcpf(1.f + __builtin_amdgcn_exp2f(-1.44269504f * x));
}
__device__ __forceinline__ float tanhf_(float x) {
  return 1.f - 2.f * __builtin_amdgcn_rcpf(1.f + __builtin_amdgcn_exp2f(2.88539008f * x));
}
__device__ __forceinline__ void gload_lds16(const void* g, void* l) {
  __builtin_amdgcn_global_load_lds(
      (const __attribute__((address_space(1))) void*)g,
      (__attribute__((address_space(3))) void*)l, 16, 0, 0);
}

// ---------------------------------------------------------------------------
// Kernel 1: Wih1 (fp32 [512][1024]) -> hi/lo bf16, pre-swizzled so that
// k_gemm1's linear global_load_lds staging yields a bank-conflict-free
// fragment-read layout.  Slot p = kt*2048 + col*4 + cp ; 16B slot (col,cp)
// of K-step kt holds k-chunk (cp ^ ((col>>1)&3)).
// ---------------------------------------------------------------------------
__global__ void k_prep(const float* __restrict__ Wih1,
                       unsigned short* __restrict__ bswh,
                       unsigned short* __restrict__ bswl) {
  int p   = blockIdx.x * 256 + threadIdx.x;    // 0..65535
  int kt  = p >> 11;
  int col = (p >> 2) & 511;
  int cp  = p & 3;
  int k0  = kt * 32 + ((cp ^ ((col >> 1) & 3)) << 3);
  const float* src = Wih1 + col * 1024 + k0;
  s16x8 vh, vl;
#pragma unroll
  for (int j = 0; j < 8; ++j) {
    float x = src[j];
    unsigned short h = bf16rne(x);
    vh[j] = (short)h;
    vl[j] = (short)bf16rne(x - bf16f(h));
  }
  *(s16x8*)(bswh + (size_t)p * 8) = vh;
  *(s16x8*)(bswl + (size_t)p * 8) = vl;
}

// ---------------------------------------------------------------------------
// Kernel 2: G1 = feats @ Wih1^T  (split bf16, 3 terms: ah*bh + al*bh + ah*bl)
// Tile: 128 rows x full N=512, BK=32, 512 threads (8 waves = 2M x 4N).
// A: fp32 global -> regs -> hi/lo bf16 LDS (padded stride 40 bf16 = 80B).
// B: global_load_lds from pre-swizzled ws arrays.
// ---------------------------------------------------------------------------
#define K2_AHI 0
#define K2_ALO 10240
#define K2_BHI 20480
#define K2_BLO 53248
#define K2_LDS 86016

__global__ __launch_bounds__(512, 2) void k_gemm1(
    const float* __restrict__ feats,
    const unsigned short* __restrict__ bswh,
    const unsigned short* __restrict__ bswl,
    float* __restrict__ G1) {
  extern __shared__ char smem[];
  const int tid  = threadIdx.x;
  const int lane = tid & 63;
  const int wv   = tid >> 6;
  const int wm   = wv >> 2;        // 0..1  (64-row slice)
  const int wn   = wv & 3;         // 0..3  (128-col slice)
  const int rowbase = blockIdx.x * 128;

  f32x4 acc[4][8] = {};            // 4 M-frags x 8 N-frags, 128 VGPR

  const int arow = tid >> 2;       // 0..127
  const int aq   = tid & 3;        // 0..3   (8-float chunk)
  const float* asrc = feats + (size_t)(rowbase + arow) * D_IN + aq * 8;
  char* ahw = smem + K2_AHI + arow * 80 + aq * 16;
  char* alw = smem + K2_ALO + arow * 80 + aq * 16;
  const int kg = lane >> 4;

#pragma unroll 1
  for (int kt = 0; kt < 32; ++kt) {
    __syncthreads();               // previous iter's frag reads done
    // --- stage B (32 KiB hi + 32 KiB lo) via global_load_lds, linear ---
#pragma unroll
    for (int i = 0; i < 4; ++i) {
      int seg = i * 8 + wv;
      size_t goff = ((size_t)kt << 15) + seg * 1024 + lane * 16;
      gload_lds16((const char*)bswh + goff, smem + K2_BHI + seg * 1024);
      gload_lds16((const char*)bswl + goff, smem + K2_BLO + seg * 1024);
    }
    // --- stage A: fp32 -> hi/lo bf16 (on the fly) ---
    {
      const float* ap = asrc + kt * 32;
      f32x4 v0 = *(const f32x4*)ap;
      f32x4 v1 = *(const f32x4*)(ap + 4);
      s16x8 hi, lo;
#pragma unroll
      for (int j = 0; j < 4; ++j) {
        unsigned short h0 = bf16rne(v0[j]);
        unsigned short h1 = bf16rne(v1[j]);
        hi[j]     = (short)h0;
        hi[4 + j] = (short)h1;
        lo[j]     = (short)bf16rne(v0[j] - bf16f(h0));
        lo[4 + j] = (short)bf16rne(v1[j] - bf16f(h1));
      }
      *(s16x8*)ahw = hi;
      *(s16x8*)alw = lo;
    }
    __syncthreads();               // staging complete
    // --- fragments + MFMA ---
    s16x8 ah[4], al[4];
#pragma unroll
    for (int mf = 0; mf < 4; ++mf) {
      int row = wm * 64 + mf * 16 + (lane & 15);
      const char* pa = smem + row * 80 + kg * 16;
      ah[mf] = *(const s16x8*)(pa + K2_AHI);
      al[mf] = *(const s16x8*)(pa + K2_ALO);
    }
#pragma unroll
    for (int nf = 0; nf < 8; ++nf) {
      int col  = wn * 128 + nf * 16 + (lane & 15);
      int coff = col * 64 + ((kg ^ ((col >> 1) & 3)) << 4);
      s16x8 bh = *(const s16x8*)(smem + K2_BHI + coff);
      s16x8 bl = *(const s16x8*)(smem + K2_BLO + coff);
#pragma unroll
      for (int mf = 0; mf < 4; ++mf) {
        acc[mf][nf] = __builtin_amdgcn_mfma_f32_16x16x32_bf16(ah[mf], bh, acc[mf][nf], 0, 0, 0);
        acc[mf][nf] = __builtin_amdgcn_mfma_f32_16x16x32_bf16(al[mf], bh, acc[mf][nf], 0, 0, 0);
        acc[mf][nf] = __builtin_amdgcn_mfma_f32_16x16x32_bf16(ah[mf], bl, acc[mf][nf], 0, 0, 0);
      }
    }
  }
  // --- epilogue: C row = (lane>>4)*4+reg (batch-row), col = lane&15 (gate) ---
#pragma unroll
  for (int mf = 0; mf < 4; ++mf) {
#pragma unroll
    for (int nf = 0; nf < 8; ++nf) {
      int row0 = rowbase + wm * 64 + mf * 16 + (lane >> 4) * 4;
      int col  = wn * 128 + nf * 16 + (lane & 15);
#pragma unroll
      for (int r = 0; r < 4; ++r)
        G1[(size_t)(row0 + r) * 512 + col] = acc[mf][nf][r];
    }
  }
}

// ---------------------------------------------------------------------------
// Kernel 3: sequential recurrence. 32 blocks x 512 threads, 16 rows/block.
// Wave w owns gate N-frags {w, w+8, w+16, w+24} -> quarter q of h-cols
// [16w,16w+16) => i/f/g/o for a lane's h-column all live in its own accs.
// ---------------------------------------------------------------------------
#define K3_W1 0            // 32 nf * 4 kf * 1024B = 128 KiB
#define K3_H1 131072       // 4 KiB (fragment-ordered bf16 h1)
#define K3_H2 135168       // 4 KiB
#define K3_LDS 139264

__global__ __launch_bounds__(512, 2) void k_lstm(
    const float* __restrict__ G1,
    const float* __restrict__ Whh1,
    const float* __restrict__ bih1, const float* __restrict__ bhh1,
    const float* __restrict__ Wih2, const float* __restrict__ Whh2,
    const float* __restrict__ bih2, const float* __restrict__ bhh2,
    float* __restrict__ out) {
  extern __shared__ char smem[];
  const int tid  = threadIdx.x;
  const int lane = tid & 63;
  const int wv   = tid >> 6;
  const int l15  = lane & 15;
  const int lhi  = lane >> 4;
  const int b0   = blockIdx.x * 16;

  // --- init: Whh1 -> fragment-ordered bf16 LDS ---
#pragma unroll 1
  for (int i = 0; i < 16; ++i) {
    int s  = tid * 16 + i;               // 8192 16B slots
    int nf = s >> 8, kf = (s >> 6) & 3, l = s & 63;
    int col = nf * 16 + (l & 15);
    int k   = kf * 32 + (l >> 4) * 8;
    const float* src = Whh1 + col * H_HID + k;
    s16x8 v;
#pragma unroll
    for (int j = 0; j < 8; ++j) v[j] = (short)bf16rne(src[j]);
    *(s16x8*)(smem + K3_W1 + (size_t)s * 16) = v;
  }
  // zero h1/h2 fragment LDS (8 KiB contiguous)
  {
    s16x8 z = {0, 0, 0, 0, 0, 0, 0, 0};
    *(s16x8*)(smem + K3_H1 + tid * 16) = z;
  }
  // --- init: [Wih2;Whh2] fragments into registers (K=256) ---
  s16x8 w2[4][8];
#pragma unroll
  for (int q = 0; q < 4; ++q) {
#pragma unroll
    for (int kf = 0; kf < 8; ++kf) {
      int col2 = (wv + 8 * q) * 16 + l15;
      int k    = kf * 32 + lhi * 8;
      const float* src = (kf < 4) ? (Wih2 + col2 * H_HID + k)
                                  : (Whh2 + col2 * H_HID + (k - 128));
      s16x8 v;
#pragma unroll
      for (int j = 0; j < 8; ++j) v[j] = (short)bf16rne(src[j]);
      w2[q][kf] = v;
    }
  }
  const int j = wv * 16 + l15;           // this lane's h-column
  float b1q[4], b2q[4];
#pragma unroll
  for (int q = 0; q < 4; ++q) {
    b1q[q] = bih1[q * 128 + j] + bhh1[q * 128 + j];
    b2q[q] = bih2[q * 128 + j] + bhh2[q * 128 + j];
  }
  float c1[4] = {0.f, 0.f, 0.f, 0.f};
  float c2[4] = {0.f, 0.f, 0.f, 0.f};
  const f32x4 zero4 = {0.f, 0.f, 0.f, 0.f};
  // h-frag write address pieces for this lane's column j
  const int kfj = j >> 5;
  const int ljo = 16 * ((j >> 3) & 3);
  const int bjo = (j & 7) * 2;
  __syncthreads();

#pragma unroll 1
  for (int t = 0; t < T_SEQ; ++t) {
    // G1 slice loads (consumed in ew1 -> latency hidden under GEMM1)
    float g1v[4][4];
#pragma unroll
    for (int r = 0; r < 4; ++r) {
      int b = b0 + lhi * 4 + r;
      const float* gp = G1 + ((size_t)(b * T_SEQ + t)) * 512 + j;
#pragma unroll
      for (int q = 0; q < 4; ++q) g1v[q][r] = gp[q * 128];
    }
    // --- GEMM1: gates1 = h1 @ Whh1^T ---
    s16x8 a1[4];
#pragma unroll
    for (int kf = 0; kf < 4; ++kf)
      a1[kf] = *(const s16x8*)(smem + K3_H1 + kf * 1024 + lane * 16);
    f32x4 acc[4];
#pragma unroll
    for (int q = 0; q < 4; ++q) acc[q] = zero4;
#pragma unroll
    for (int q = 0; q < 4; ++q) {
#pragma unroll
      for (int kf = 0; kf < 4; ++kf) {
        s16x8 bw = *(const s16x8*)(smem + K3_W1 + (wv + 8 * q) * 4096 + kf * 1024 + lane * 16);
        acc[q] = __builtin_amdgcn_mfma_f32_16x16x32_bf16(a1[kf], bw, acc[q], 0, 0, 0);
      }
    }
    __syncthreads();                     // BAR1: all h1 reads done
    // --- cell 1 ---
    float h1v[4];
#pragma unroll
    for (int r = 0; r < 4; ++r) {
      float pi = acc[0][r] + g1v[0][r] + b1q[0];
      float pf = acc[1][r] + g1v[1][r] + b1q[1];
      float pg = acc[2][r] + g1v[2][r] + b1q[2];
      float po = acc[3][r] + g1v[3][r] + b1q[3];
      float iv = sigf(pi), fv = sigf(pf), gv = tanhf_(pg), ov = sigf(po);
      c1[r]  = fv * c1[r] + iv * gv;
      h1v[r] = ov * tanhf_(c1[r]);
    }
#pragma unroll
    for (int r = 0; r < 4; ++r) {
      int mrow = lhi * 4 + r;
      *(short*)(smem + K3_H1 + kfj * 1024 + (mrow + ljo) * 16 + bjo) = (short)bf16rne(h1v[r]);
    }
    __syncthreads();                     // BAR2: h1_new visible
    // --- GEMM2: gates2 = [h1,h2] @ [Wih2;Whh2]^T (B from registers) ---
    s16x8 a2[8];
#pragma unroll
    for (int kf = 0; kf < 4; ++kf) {
      a2[kf]     = *(const s16x8*)(smem + K3_H1 + kf * 1024 + lane * 16);
      a2[4 + kf] = *(const s16x8*)(smem + K3_H2 + kf * 1024 + lane * 16);
    }
    f32x4 acc2[4];
#pragma unroll
    for (int q = 0; q < 4; ++q) acc2[q] = zero4;
#pragma unroll
    for (int q = 0; q < 4; ++q) {
#pragma unroll
      for (int kf = 0; kf < 8; ++kf)
        acc2[q] = __builtin_amdgcn_mfma_f32_16x16x32_bf16(a2[kf], w2[q][kf], acc2[q], 0, 0, 0);
    }
    __syncthreads();                     // BAR3: all h2 reads done
    // --- cell 2 ---
    float h2v[4];
#pragma unroll
    for (int r = 0; r < 4; ++r) {
      float pi = acc2[0][r] + b2q[0];
      float pf = acc2[1][r] + b2q[1];
      float pg = acc2[2][r] + b2q[2];
      float po = acc2[3][r] + b2q[3];
      float iv = sigf(pi), fv = sigf(pf), gv = tanhf_(pg), ov = sigf(po);
      c2[r]  = fv * c2[r] + iv * gv;
      h2v[r] = ov * tanhf_(c2[r]);
    }
#pragma unroll
    for (int r = 0; r < 4; ++r) {
      int mrow = lhi * 4 + r;
      *(short*)(smem + K3_H2 + kfj * 1024 + (mrow + ljo) * 16 + bjo) = (short)bf16rne(h2v[r]);
    }
    if (t == T_SEQ - 1) {
#pragma unroll
      for (int r = 0; r < 4; ++r)
        out[(size_t)(b0 + lhi * 4 + r) * H_HID + j] = h2v[r];
    }
    __syncthreads();                     // BAR4: h2_new visible
  }
}

// ---------------------------------------------------------------------------
extern "C" void kernel_launch(void* const* d_in, const int* in_sizes, int n_in,
                              void* d_out, int out_size, void* d_ws, size_t ws_size,
                              hipStream_t stream) {
  (void)in_sizes; (void)n_in; (void)out_size; (void)ws_size;
  const float* feats = (const float*)d_in[0];
  const float* Wih1  = (const float*)d_in[1];
  const float* Whh1  = (const float*)d_in[2];
  const float* bih1  = (const float*)d_in[3];
  const float* bhh1  = (const float*)d_in[4];
  const float* Wih2  = (const float*)d_in[5];
  const float* Whh2  = (const float*)d_in[6];
  const float* bih2  = (const float*)d_in[7];
  const float* bhh2  = (const float*)d_in[8];
  float* out = (float*)d_out;

  char* ws = (char*)d_ws;
  float* G1 = (float*)ws;                                        // 134,217,728 B
  unsigned short* bswh = (unsigned short*)(ws + 134217728);      // 1 MiB
  unsigned short* bswl = (unsigned short*)(ws + 134217728 + 1048576);

  // allow >64KiB dynamic LDS (idempotent, safe under graph capture)
  hipFuncSetAttribute((const void*)k_gemm1, hipFuncAttributeMaxDynamicSharedMemorySize, K2_LDS);
  hipFuncSetAttribute((const void*)k_lstm,  hipFuncAttributeMaxDynamicSharedMemorySize, K3_LDS);

  k_prep<<<256, 256, 0, stream>>>(Wih1, bswh, bswl);
  k_gemm1<<<512, 512, K2_LDS, stream>>>(feats, bswh, bswl, G1);
  k_lstm<<<32, 512, K3_LDS, stream>>>(G1, Whh1, bih1, bhh1, Wih2, Whh2, bih2, bhh2, out);
}

// Round 2
// 733.988 us; speedup vs baseline: 1.2102x; 1.2102x over previous
//
#include <hip/hip_runtime.h>
#include <hip/hip_bf16.h>

// 2-layer LSTM, B=512 T=128 D=1024 H=128, fp32 in/out.
// Phase A (k_prep + k_gemm1): G1[t][b][4H] = feats @ Wih1^T + (bih1+bhh1),
//   split-bf16 (hi/lo, 3 MFMA terms ~ fp32 exact). 64x256 tiles, 3 blocks/CU.
// Phase B (k_lstm): 32 blocks x 16 batch rows, 8 waves. Whh1 in LDS
//   (fragment-ordered bf16), [Wih2;Whh2] pre-fragged bf16 in ws, reloaded
//   per step in 2 chunks (coalesced, latency-hidden). h1/h2 double-buffered
//   fragment LDS -> ONE barrier/step. G1 prefetched one step ahead.

using f32x4 = __attribute__((ext_vector_type(4))) float;
using s16x8 = __attribute__((ext_vector_type(8))) short;

#define T_SEQ 128
#define D_IN  1024
#define H_HID 128

__device__ __forceinline__ unsigned short bf16rne(float x) {
  unsigned int b = __builtin_bit_cast(unsigned int, x);
  b = (b + 0x7FFFu + ((b >> 16) & 1u)) >> 16;   // round-to-nearest-even
  return (unsigned short)b;
}
__device__ __forceinline__ float bf16f(unsigned short h) {
  unsigned int b = ((unsigned int)h) << 16;
  return __builtin_bit_cast(float, b);
}
__device__ __forceinline__ float sigf(float x) {
  return __builtin_amdgcn_rcpf(1.f + __builtin_amdgcn_exp2f(-1.44269504f * x));
}
__device__ __forceinline__ float tanhf_(float x) {
  return 1.f - 2.f * __builtin_amdgcn_rcpf(1.f + __builtin_amdgcn_exp2f(2.88539008f * x));
}
__device__ __forceinline__ void gload_lds16(const void* g, void* l) {
  __builtin_amdgcn_global_load_lds(
      (const __attribute__((address_space(1))) void*)g,
      (__attribute__((address_space(3))) void*)l, 16, 0, 0);
}

// ---------------------------------------------------------------------------
// Kernel 1:
//  blocks 0..255 : Wih1 (fp32 [512][1024]) -> hi/lo bf16, pre-swizzled so
//    k_gemm1's linear global_load_lds staging is bank-conflict-free on read.
//    Slot p = kt*2048 + col*4 + cp ; slot holds k-chunk (cp ^ ((col>>1)&3)).
//  blocks 256..319 : [Wih2;Whh2] -> fragment-ordered bf16 (w2g), so k_lstm
//    loads MFMA B-fragments directly with coalesced dwordx4.
// ---------------------------------------------------------------------------
__global__ void k_prep(const float* __restrict__ Wih1,
                       const float* __restrict__ Wih2,
                       const float* __restrict__ Whh2,
                       unsigned short* __restrict__ bswh,
                       unsigned short* __restrict__ bswl,
                       unsigned short* __restrict__ w2g) {
  if (blockIdx.x < 256) {
    int p   = blockIdx.x * 256 + threadIdx.x;    // 0..65535
    int kt  = p >> 11;
    int col = (p >> 2) & 511;
    int cp  = p & 3;
    int k0  = kt * 32 + ((cp ^ ((col >> 1) & 3)) << 3);
    const float* src = Wih1 + col * 1024 + k0;
    s16x8 vh, vl;
#pragma unroll
    for (int jj = 0; jj < 8; ++jj) {
      float x = src[jj];
      unsigned short h = bf16rne(x);
      vh[jj] = (short)h;
      vl[jj] = (short)bf16rne(x - bf16f(h));
    }
    *(s16x8*)(bswh + (size_t)p * 8) = vh;
    *(s16x8*)(bswl + (size_t)p * 8) = vl;
  } else {
    int p2 = (blockIdx.x - 256) * 256 + threadIdx.x;   // 0..16383
    int wv2  = p2 >> 11;          // 0..7
    int q    = (p2 >> 9) & 3;     // 0..3
    int kf   = (p2 >> 6) & 7;     // 0..7
    int lane = p2 & 63;
    int col2 = (wv2 + 8 * q) * 16 + (lane & 15);
    int k    = kf * 32 + (lane >> 4) * 8;
    const float* src = (kf < 4) ? (Wih2 + col2 * H_HID + k)
                                : (Whh2 + col2 * H_HID + (k - 128));
    s16x8 v;
#pragma unroll
    for (int jj = 0; jj < 8; ++jj) v[jj] = (short)bf16rne(src[jj]);
    *(s16x8*)(w2g + (size_t)p2 * 8) = v;
  }
}

// ---------------------------------------------------------------------------
// Kernel 2: G1 = feats @ Wih1^T + bias1  (split bf16, 3 terms)
// Tile: 64 rows x 256 cols, BK=32, 256 threads (4 waves, 64 cols each).
// LDS 43008 B -> 3 blocks/CU. Output layout G1[t][b][512].
// ---------------------------------------------------------------------------
#define K2_AHI 0
#define K2_ALO 5120
#define K2_BHI 10240
#define K2_BLO 26624
#define K2_LDS 43008

__global__ __launch_bounds__(256, 3) void k_gemm1(
    const float* __restrict__ feats,
    const unsigned short* __restrict__ bswh,
    const unsigned short* __restrict__ bswl,
    const float* __restrict__ bih1, const float* __restrict__ bhh1,
    float* __restrict__ G1) {
  extern __shared__ char smem[];
  const int tid  = threadIdx.x;
  const int lane = tid & 63;
  const int wv   = tid >> 6;           // 0..3
  const int rows0 = (blockIdx.x >> 1) << 6;   // 64-row tile (one batch b)
  const int c0    = (blockIdx.x & 1) << 8;    // 0 or 256

  f32x4 acc[4][4] = {};                // 4 M-frags x 4 N-frags = 64 VGPR

  const int arow = tid >> 2;           // 0..63
  const int aq   = tid & 3;            // 8-float chunk
  const float* asrc = feats + (size_t)(rows0 + arow) * D_IN + aq * 8;
  char* ahw = smem + K2_AHI + arow * 80 + aq * 16;
  char* alw = smem + K2_ALO + arow * 80 + aq * 16;
  const int kg  = lane >> 4;
  const int l15 = lane & 15;

#pragma unroll 1
  for (int kt = 0; kt < 32; ++kt) {
    __syncthreads();               // previous iter's frag reads done
    // --- stage B (16 KiB hi + 16 KiB lo), linear dest, pre-swizzled src ---
#pragma unroll
    for (int i = 0; i < 4; ++i) {
      int seg = i * 4 + wv;
      size_t goff = ((size_t)kt << 15) + ((size_t)c0 << 6) + seg * 1024 + lane * 16;
      gload_lds16((const char*)bswh + goff, smem + K2_BHI + seg * 1024);
      gload_lds16((const char*)bswl + goff, smem + K2_BLO + seg * 1024);
    }
    // --- stage A: fp32 -> hi/lo bf16 on the fly (64 rows x 32 k) ---
    {
      const float* ap = asrc + kt * 32;
      f32x4 v0 = *(const f32x4*)ap;
      f32x4 v1 = *(const f32x4*)(ap + 4);
      s16x8 hi, lo;
#pragma unroll
      for (int jj = 0; jj < 4; ++jj) {
        unsigned short h0 = bf16rne(v0[jj]);
        unsigned short h1 = bf16rne(v1[jj]);
        hi[jj]     = (short)h0;
        hi[4 + jj] = (short)h1;
        lo[jj]     = (short)bf16rne(v0[jj] - bf16f(h0));
        lo[4 + jj] = (short)bf16rne(v1[jj] - bf16f(h1));
      }
      *(s16x8*)ahw = hi;
      *(s16x8*)alw = lo;
    }
    __syncthreads();               // staging complete
    // --- fragments + MFMA ---
    s16x8 ah[4], al[4];
#pragma unroll
    for (int mf = 0; mf < 4; ++mf) {
      int row = mf * 16 + l15;
      const char* pa = smem + row * 80 + kg * 16;
      ah[mf] = *(const s16x8*)(pa + K2_AHI);
      al[mf] = *(const s16x8*)(pa + K2_ALO);
    }
#pragma unroll
    for (int nf = 0; nf < 4; ++nf) {
      int cc   = wv * 64 + nf * 16 + l15;
      int coff = cc * 64 + ((kg ^ ((cc >> 1) & 3)) << 4);
      s16x8 bh = *(const s16x8*)(smem + K2_BHI + coff);
      s16x8 bl = *(const s16x8*)(smem + K2_BLO + coff);
#pragma unroll
      for (int mf = 0; mf < 4; ++mf) {
        acc[mf][nf] = __builtin_amdgcn_mfma_f32_16x16x32_bf16(ah[mf], bh, acc[mf][nf], 0, 0, 0);
        acc[mf][nf] = __builtin_amdgcn_mfma_f32_16x16x32_bf16(al[mf], bh, acc[mf][nf], 0, 0, 0);
        acc[mf][nf] = __builtin_amdgcn_mfma_f32_16x16x32_bf16(ah[mf], bl, acc[mf][nf], 0, 0, 0);
      }
    }
  }
  // --- epilogue: add bias1, write G1[t][b][gate] ---
#pragma unroll
  for (int nf = 0; nf < 4; ++nf) {
    int gcol = c0 + wv * 64 + nf * 16 + l15;
    float bv = bih1[gcol] + bhh1[gcol];
#pragma unroll
    for (int mf = 0; mf < 4; ++mf) {
      int grow0 = rows0 + mf * 16 + (lane >> 4) * 4;
#pragma unroll
      for (int r = 0; r < 4; ++r) {
        int grow = grow0 + r;
        int bb = grow >> 7;        // batch
        int tt = grow & 127;       // time
        G1[((size_t)tt * 512 + bb) * 512 + gcol] = acc[mf][nf][r] + bv;
      }
    }
  }
}

// ---------------------------------------------------------------------------
// Kernel 3: recurrence. 32 blocks x 512 threads, 16 batch rows/block.
// Wave w owns gate N-frags {w, w+8, w+16, w+24} -> i/f/g/o for h-cols
// [16w,16w+16) live in its own accumulators. One barrier per step.
// ---------------------------------------------------------------------------
#define K3_W1 0            // 32 nf * 4 kf * 1024B = 128 KiB
#define K3_H1 131072       // 2 x 4 KiB (double-buffered frag-ordered bf16 h1)
#define K3_H2 139264       // 2 x 4 KiB
#define K3_LDS 147456

__global__ __launch_bounds__(512, 2) void k_lstm(
    const float* __restrict__ G1,
    const float* __restrict__ Whh1,
    const unsigned short* __restrict__ w2g,
    const float* __restrict__ bih2, const float* __restrict__ bhh2,
    float* __restrict__ out) {
  extern __shared__ char smem[];
  const int tid  = threadIdx.x;
  const int lane = tid & 63;
  const int wv   = tid >> 6;
  const int l15  = lane & 15;
  const int lhi  = lane >> 4;
  const int b0   = blockIdx.x * 16;

  // --- init: Whh1 -> fragment-ordered bf16 LDS ---
#pragma unroll 1
  for (int i = 0; i < 16; ++i) {
    int s  = tid * 16 + i;               // 8192 16B slots
    int nf = s >> 8, kf = (s >> 6) & 3, l = s & 63;
    int col = nf * 16 + (l & 15);
    int k   = kf * 32 + (l >> 4) * 8;
    const float* src = Whh1 + col * H_HID + k;
    s16x8 v;
#pragma unroll
    for (int jj = 0; jj < 8; ++jj) v[jj] = (short)bf16rne(src[jj]);
    *(s16x8*)(smem + K3_W1 + (size_t)s * 16) = v;
  }
  // zero all four h frag buffers (16 KiB contiguous)
  {
    s16x8 z = {0, 0, 0, 0, 0, 0, 0, 0};
    *(s16x8*)(smem + K3_H1 + tid * 32) = z;
    *(s16x8*)(smem + K3_H1 + tid * 32 + 16) = z;
  }
  const int j = wv * 16 + l15;           // this lane's h-column
  float b2q[4];
#pragma unroll
  for (int q = 0; q < 4; ++q) b2q[q] = bih2[q * 128 + j] + bhh2[q * 128 + j];
  float c1[4] = {0.f, 0.f, 0.f, 0.f};
  float c2[4] = {0.f, 0.f, 0.f, 0.f};
  // h-frag write address pieces for this lane's column j
  const int kfj = j >> 5;
  const int ljo = 16 * ((j >> 3) & 3);
  const int bjo = (j & 7) * 2;
  const char* w2c = (const char*)w2g + (size_t)wv * 32768;

  // prologue: G1 slice for t=0 (layout [t][b][512], bias already folded)
  float g1v[4][4];
  {
    const float* gp = G1 + ((size_t)(b0 + lhi * 4)) * 512 + j;
#pragma unroll
    for (int r = 0; r < 4; ++r)
#pragma unroll
      for (int q = 0; q < 4; ++q) g1v[q][r] = gp[r * 512 + q * 128];
  }
  __syncthreads();

#pragma unroll 1
  for (int t = 0; t < T_SEQ; ++t) {
    const int pb = (t & 1) << 12;        // current buffer offset (0/4096)
    const int nb = 4096 - pb;            // next buffer offset
    // --- W2 chunk A (gate quarters 0,1) — issue early, consumed in GEMM2 ---
    s16x8 w2a[2][8];
#pragma unroll
    for (int q = 0; q < 2; ++q)
#pragma unroll
      for (int kf = 0; kf < 8; ++kf)
        w2a[q][kf] = *(const s16x8*)(w2c + ((q * 8 + kf) * 64 + lane) * 16);
    // --- GEMM1: gates1 = h1 @ Whh1^T  (acc init = G1 slice incl. bias) ---
    s16x8 a1[4];
#pragma unroll
    for (int kf = 0; kf < 4; ++kf)
      a1[kf] = *(const s16x8*)(smem + K3_H1 + pb + kf * 1024 + lane * 16);
    f32x4 acc[4];
#pragma unroll
    for (int q = 0; q < 4; ++q) {
      f32x4 iv = {g1v[q][0], g1v[q][1], g1v[q][2], g1v[q][3]};
      acc[q] = iv;
    }
#pragma unroll
    for (int q = 0; q < 4; ++q) {
#pragma unroll
      for (int kf = 0; kf < 4; ++kf) {
        s16x8 bw = *(const s16x8*)(smem + K3_W1 + (wv + 8 * q) * 4096 + kf * 1024 + lane * 16);
        acc[q] = __builtin_amdgcn_mfma_f32_16x16x32_bf16(a1[kf], bw, acc[q], 0, 0, 0);
      }
    }
    // --- prefetch G1 for t+1 (consumed next iteration) ---
    float g1n[4][4];
    {
      int tn = (t < T_SEQ - 1) ? t + 1 : T_SEQ - 1;
      const float* gp = G1 + ((size_t)tn * 512 + b0 + lhi * 4) * 512 + j;
#pragma unroll
      for (int r = 0; r < 4; ++r)
#pragma unroll
        for (int q = 0; q < 4; ++q) g1n[q][r] = gp[r * 512 + q * 128];
    }
    // --- cell 1 ---
    float h1v[4];
#pragma unroll
    for (int r = 0; r < 4; ++r) {
      float iv = sigf(acc[0][r]), fv = sigf(acc[1][r]);
      float gv = tanhf_(acc[2][r]), ov = sigf(acc[3][r]);
      c1[r]  = fv * c1[r] + iv * gv;
      h1v[r] = ov * tanhf_(c1[r]);
    }
#pragma unroll
    for (int r = 0; r < 4; ++r) {
      int mrow = lhi * 4 + r;
      *(short*)(smem + K3_H1 + nb + kfj * 1024 + (mrow + ljo) * 16 + bjo) = (short)bf16rne(h1v[r]);
    }
    __syncthreads();                     // the ONLY barrier per step
    // --- W2 chunk B (gate quarters 2,3) ---
    s16x8 w2b[2][8];
#pragma unroll
    for (int q = 0; q < 2; ++q)
#pragma unroll
      for (int kf = 0; kf < 8; ++kf)
        w2b[q][kf] = *(const s16x8*)(w2c + (((q + 2) * 8 + kf) * 64 + lane) * 16);
    // --- GEMM2: gates2 = [h1,h2] @ [Wih2;Whh2]^T ---
    s16x8 a2[8];
#pragma unroll
    for (int kf = 0; kf < 4; ++kf) {
      a2[kf]     = *(const s16x8*)(smem + K3_H1 + nb + kf * 1024 + lane * 16);
      a2[4 + kf] = *(const s16x8*)(smem + K3_H2 + pb + kf * 1024 + lane * 16);
    }
    f32x4 acc2[4];
#pragma unroll
    for (int q = 0; q < 4; ++q) {
      f32x4 iv = {b2q[q], b2q[q], b2q[q], b2q[q]};
      acc2[q] = iv;
    }
#pragma unroll
    for (int q = 0; q < 2; ++q)
#pragma unroll
      for (int kf = 0; kf < 8; ++kf)
        acc2[q] = __builtin_amdgcn_mfma_f32_16x16x32_bf16(a2[kf], w2a[q][kf], acc2[q], 0, 0, 0);
#pragma unroll
    for (int q = 0; q < 2; ++q)
#pragma unroll
      for (int kf = 0; kf < 8; ++kf)
        acc2[q + 2] = __builtin_amdgcn_mfma_f32_16x16x32_bf16(a2[kf], w2b[q][kf], acc2[q + 2], 0, 0, 0);
    // --- cell 2 ---
    float h2v[4];
#pragma unroll
    for (int r = 0; r < 4; ++r) {
      float iv = sigf(acc2[0][r]), fv = sigf(acc2[1][r]);
      float gv = tanhf_(acc2[2][r]), ov = sigf(acc2[3][r]);
      c2[r]  = fv * c2[r] + iv * gv;
      h2v[r] = ov * tanhf_(c2[r]);
    }
#pragma unroll
    for (int r = 0; r < 4; ++r) {
      int mrow = lhi * 4 + r;
      *(short*)(smem + K3_H2 + nb + kfj * 1024 + (mrow + ljo) * 16 + bjo) = (short)bf16rne(h2v[r]);
    }
    if (t == T_SEQ - 1) {
#pragma unroll
      for (int r = 0; r < 4; ++r)
        out[(size_t)(b0 + lhi * 4 + r) * H_HID + j] = h2v[r];
    }
    // --- rotate prefetched G1 ---
#pragma unroll
    for (int q = 0; q < 4; ++q)
#pragma unroll
      for (int r = 0; r < 4; ++r) g1v[q][r] = g1n[q][r];
  }
}

// ---------------------------------------------------------------------------
extern "C" void kernel_launch(void* const* d_in, const int* in_sizes, int n_in,
                              void* d_out, int out_size, void* d_ws, size_t ws_size,
                              hipStream_t stream) {
  (void)in_sizes; (void)n_in; (void)out_size; (void)ws_size;
  const float* feats = (const float*)d_in[0];
  const float* Wih1  = (const float*)d_in[1];
  const float* Whh1  = (const float*)d_in[2];
  const float* bih1  = (const float*)d_in[3];
  const float* bhh1  = (const float*)d_in[4];
  const float* Wih2  = (const float*)d_in[5];
  const float* Whh2  = (const float*)d_in[6];
  const float* bih2  = (const float*)d_in[7];
  const float* bhh2  = (const float*)d_in[8];
  float* out = (float*)d_out;

  char* ws = (char*)d_ws;
  float* G1 = (float*)ws;                                        // 134,217,728 B
  unsigned short* bswh = (unsigned short*)(ws + 134217728);      // 1 MiB
  unsigned short* bswl = (unsigned short*)(ws + 134217728 + 1048576);
  unsigned short* w2g  = (unsigned short*)(ws + 134217728 + 2097152);  // 256 KiB

  hipFuncSetAttribute((const void*)k_gemm1, hipFuncAttributeMaxDynamicSharedMemorySize, K2_LDS);
  hipFuncSetAttribute((const void*)k_lstm,  hipFuncAttributeMaxDynamicSharedMemorySize, K3_LDS);

  k_prep<<<320, 256, 0, stream>>>(Wih1, Wih2, Whh2, bswh, bswl, w2g);
  k_gemm1<<<2048, 256, K2_LDS, stream>>>(feats, bswh, bswl, bih1, bhh1, G1);
  k_lstm<<<32, 512, K3_LDS, stream>>>(G1, Whh1, w2g, bih2, bhh2, out);
}